// Round 7
// baseline (180.990 us; speedup 1.0000x reference)
//
#include <hip/hip_runtime.h>

typedef __attribute__((ext_vector_type(8))) short bf16x8;
typedef __attribute__((ext_vector_type(4))) float f32x4;
typedef __attribute__((ext_vector_type(4))) unsigned short us4;

#define T_SEQ 2048
#define DMODEL 2048
#define NH 16
#define NKV 4
#define HD 128
#define STRQKV 5120   /* NH*HD*2 + 2*NKV*HD : fused QKV output row stride */
#define QOFF 0        /* q/gate cols 0..4095 */
#define KOFF 4096     /* k cols 4096..4607 */
#define VOFF 4608     /* v cols 4608..5119 */
#define ATT_SCALE 0.08838834764831845f

__device__ __forceinline__ float bf2f(unsigned short u) {
  union { unsigned int u; float f; } v; v.u = ((unsigned int)u) << 16; return v.f;
}
__device__ __forceinline__ unsigned short f2bf(float f) {
  union { float f; unsigned int u; } v; v.f = f;
  unsigned int u = v.u;
  return (unsigned short)((u + 0x7fffu + ((u >> 16) & 1u)) >> 16);
}
__device__ __forceinline__ f32x4 mfma16(bf16x8 a, bf16x8 b, f32x4 c) {
  return __builtin_amdgcn_mfma_f32_16x16x32_bf16(a, b, c, 0, 0, 0);
}
__device__ __forceinline__ void gload16(const void* g, void* l) {
  __builtin_amdgcn_global_load_lds(
      (const __attribute__((address_space(1))) unsigned int*)g,
      (__attribute__((address_space(3))) unsigned int*)l, 16, 0, 0);
}

// ---------------- fp32 -> bf16 elementwise (hidden) ----------------
__global__ __launch_bounds__(256) void convert_x(const float* __restrict__ in,
                                                 unsigned short* __restrict__ out, int n4) {
  int i = blockIdx.x * 256 + threadIdx.x;
  if (i >= n4) return;
  float4 v = ((const float4*)in)[i];
  us4 o; o.x = f2bf(v.x); o.y = f2bf(v.y); o.z = f2bf(v.z); o.w = f2bf(v.w);
  ((us4*)out)[i] = o;
}

// ---------------- fp32 [K][N] -> bf16 [N][K] transpose ----------------
__global__ __launch_bounds__(256) void transpose_f32_to_bf16(
    const float* __restrict__ in, unsigned short* __restrict__ out, int K, int N) {
  __shared__ unsigned short tile[32][33];
  int nb = blockIdx.x * 32, kb = blockIdx.y * 32;
  int tx = threadIdx.x & 31, ty = threadIdx.x >> 5;
#pragma unroll
  for (int i = 0; i < 32; i += 8)
    tile[ty + i][tx] = f2bf(in[(size_t)(kb + ty + i) * N + nb + tx]);
  __syncthreads();
#pragma unroll
  for (int i = 0; i < 32; i += 8)
    out[(size_t)(nb + ty + i) * K + kb + tx] = tile[tx][ty + i];
}

// ---------------- bf16 V (inside QKV, stride 5120) -> [NKV][HD][T] ----------------
__global__ __launch_bounds__(256) void transpose_v(const unsigned short* __restrict__ qkv,
                                                   unsigned short* __restrict__ vTg) {
  __shared__ unsigned short tile[32][33];
  int tb = blockIdx.x * 32, db = blockIdx.y * 32, kvh = blockIdx.z;
  int tx = threadIdx.x & 31, ty = threadIdx.x >> 5;
#pragma unroll
  for (int i = 0; i < 32; i += 8)
    tile[ty + i][tx] = qkv[(size_t)(tb + ty + i) * STRQKV + VOFF + kvh * HD + db + tx];
  __syncthreads();
#pragma unroll
  for (int i = 0; i < 32; i += 8)
    vTg[((size_t)kvh * HD + db + ty + i) * T_SEQ + tb + tx] = tile[tx][ty + i];
}

// ---------------- GEMM: C[M][N] = A[M][K] * B^T  (B stored [N][K]) ----------------
// 128x128 tile, 4 waves (2x2). 4-buffer depth-2 counted-vmcnt pipeline:
// stage tile t+2 -> s_waitcnt vmcnt(8) (own tile-t DMA done, t+1/t+2 in
// flight) -> raw s_barrier -> ds_read + MFMA. Never vmcnt(0) in-loop (T4).
// LDS slot swizzle slot = g ^ ((row^(row>>2))&3) applied on BOTH the staging
// global source and the ds_read side (G21 involution) -> each quarter-wave
// read covers all 32 banks uniformly (2 lanes/bank = free).
template <typename OT>
__global__ __launch_bounds__(256) void gemm_bt(const unsigned short* __restrict__ A,
                                               const unsigned short* __restrict__ B,
                                               OT* __restrict__ C, int M, int N, int K) {
  __shared__ unsigned short As[4][128 * 32];
  __shared__ unsigned short Bs[4][128 * 32];
  const int tid = threadIdx.x;
  const int wave = tid >> 6, lane = tid & 63;
  const int wr = wave >> 1, wc = wave & 1;
  const int g = lane >> 4, lr = lane & 15;
  const int row0 = blockIdx.y * 128, col0 = blockIdx.x * 128;

  // staging: thread t -> LDS linear elem t*8 (row rl = t>>2, slot sl = t&3).
  // slot sl holds logical k-chunk sl ^ f(rl), f(r) = (r ^ (r>>2)) & 3.
  const int rl = tid >> 2, sl = tid & 3;
  const int gsw = sl ^ ((rl ^ (rl >> 2)) & 3);
  const unsigned short* Ap = A + (size_t)(row0 + rl) * K + gsw * 8;
  const unsigned short* Bp = B + (size_t)(col0 + rl) * K + gsw * 8;
  const size_t half = (size_t)64 * K;  // rows +64: f unchanged (low bits same)

  auto stage = [&](int buf, int k0) {
    gload16(Ap + k0,        &As[buf][tid * 8]);
    gload16(Ap + half + k0, &As[buf][2048 + tid * 8]);
    gload16(Bp + k0,        &Bs[buf][tid * 8]);
    gload16(Bp + half + k0, &Bs[buf][2048 + tid * 8]);
  };

  const int NT = K >> 5;
  stage(0, 0);
  stage(1, 32);

  const int fsw = (lr ^ (lr >> 2)) & 3;  // read-side slot xor (per-thread const)
  f32x4 acc[4][4] = {};

  for (int t = 0; t < NT; ++t) {
    if (t + 2 < NT) {
      stage((t + 2) & 3, (t + 2) << 5);
      asm volatile("s_waitcnt vmcnt(8)" ::: "memory");
    } else if (t + 1 < NT) {
      asm volatile("s_waitcnt vmcnt(4)" ::: "memory");
    } else {
      asm volatile("s_waitcnt vmcnt(0)" ::: "memory");
    }
    __builtin_amdgcn_s_barrier();
    __builtin_amdgcn_sched_barrier(0);

    const unsigned short* as = As[t & 3];
    const unsigned short* bs = Bs[t & 3];
    bf16x8 af[4], bfr[4];
#pragma unroll
    for (int m = 0; m < 4; ++m)
      af[m] = *(const bf16x8*)(&as[(wr * 64 + m * 16 + lr) * 32 + ((g ^ fsw) * 8)]);
#pragma unroll
    for (int n = 0; n < 4; ++n)
      bfr[n] = *(const bf16x8*)(&bs[(wc * 64 + n * 16 + lr) * 32 + ((g ^ fsw) * 8)]);
    __builtin_amdgcn_s_setprio(1);
#pragma unroll
    for (int m = 0; m < 4; ++m)
#pragma unroll
      for (int n = 0; n < 4; ++n)
        acc[m][n] = mfma16(af[m], bfr[n], acc[m][n]);
    __builtin_amdgcn_s_setprio(0);
  }

#pragma unroll
  for (int m = 0; m < 4; ++m)
#pragma unroll
    for (int n = 0; n < 4; ++n)
#pragma unroll
      for (int r = 0; r < 4; ++r) {
        int row = row0 + wr * 64 + m * 16 + g * 4 + r;
        int col = col0 + wc * 64 + n * 16 + lr;
        float v = acc[m][n][r];
        if constexpr (sizeof(OT) == 2) C[(size_t)row * N + col] = f2bf(v);
        else                            C[(size_t)row * N + col] = v;
      }
}

// ---------------- RMSNorm + RoPE for K only (IN PLACE in QKV buffer) ----------------
__global__ __launch_bounds__(128) void rms_rope_k(
    unsigned short* __restrict__ qkv,
    const float* __restrict__ cosb, const float* __restrict__ sinb,
    const float* __restrict__ knw) {
  int t = blockIdx.x;
  int kh = blockIdx.y;  // 0..3
  int d = threadIdx.x;  // 0..127
  size_t addr = (size_t)t * STRQKV + KOFF + kh * HD + d;
  float x = bf2f(qkv[addr]);
  float ss = x * x;
#pragma unroll
  for (int mk = 1; mk < 64; mk <<= 1) ss += __shfl_xor(ss, mk, 64);
  __shared__ float red[2];
  __shared__ float xs[128];
  if ((d & 63) == 0) red[d >> 6] = ss;
  __syncthreads();
  float rstd = rsqrtf((red[0] + red[1]) * (1.0f / 128.0f) + 1e-6f);
  float xn = x * rstd * knw[d];
  xs[d] = xn;
  __syncthreads();
  float other = (d < 64) ? -xs[d + 64] : xs[d - 64];
  float c = cosb[(size_t)t * HD + d];
  float s = sinb[(size_t)t * HD + d];
  qkv[addr] = f2bf(xn * c + other * s);
}

// ---------------- Flash attention + gate (Q norm/rope fused) ----------------
__global__ __launch_bounds__(256) void attn_kernel(
    const unsigned short* __restrict__ qkv, const unsigned short* __restrict__ vTg,
    const int* __restrict__ seg,
    const float* __restrict__ cosb, const float* __restrict__ sinb,
    const float* __restrict__ qnw,
    unsigned short* __restrict__ attnb) {
  const int bid = blockIdx.x;
  const int h = bid & 15;
  const int j = bid >> 4;
  const int qb = (j < 16) ? j : 47 - j;   // co-resident pairing: qb + (31-qb)
  const int kvh = h >> 2;
  const int tid = threadIdx.x;
  const int wave = tid >> 6, lane = tid & 63;
  const int g = lane >> 4, lr = lane & 15;
  const int qrow0 = qb * 64 + wave * 16;

  __shared__ unsigned short Ks[2][64 * 128];
  __shared__ unsigned short Vt[2][128 * 64];
  __shared__ unsigned short Plds[4][16][72];

  const int krow_s = tid >> 4;
  const int kcol_s = tid & 15;
  const int vrow_s = tid >> 3;
  const int vcol_s = tid & 7;

  const unsigned short* Kbase = qkv + KOFF + kvh * HD;        // row stride STRQKV
  const unsigned short* Vbase = vTg + (size_t)kvh * HD * T_SEQ;

  // ---- fused Q RMSNorm + RoPE + scale -> bf16 A-fragments ----
  const int t0 = qrow0 + lr;
  float xn[4][8];
  {
    float ssl = 0.f;
#pragma unroll
    for (int c = 0; c < 4; ++c) {
      bf16x8 tq = *(const bf16x8*)(qkv + (size_t)t0 * STRQKV + h * 256 + c * 32 + g * 8);
#pragma unroll
      for (int i = 0; i < 8; ++i) {
        float x = bf2f((unsigned short)tq[i]);
        xn[c][i] = x;
        ssl += x * x;
      }
    }
    ssl += __shfl_xor(ssl, 16, 64);
    ssl += __shfl_xor(ssl, 32, 64);
    float rstd = rsqrtf(ssl * (1.0f / 128.0f) + 1e-6f);
#pragma unroll
    for (int c = 0; c < 4; ++c)
#pragma unroll
      for (int i = 0; i < 8; ++i)
        xn[c][i] *= rstd * qnw[c * 32 + g * 8 + i];
  }
  bf16x8 qf[4];
#pragma unroll
  for (int c = 0; c < 4; ++c)
#pragma unroll
    for (int i = 0; i < 8; ++i) {
      int d = c * 32 + g * 8 + i;
      float rot = (c < 2) ? -xn[c + 2][i] : xn[c - 2][i];
      float ov = xn[c][i] * cosb[(size_t)t0 * HD + d] + rot * sinb[(size_t)t0 * HD + d];
      qf[c][i] = (short)f2bf(ov * ATT_SCALE);
    }

  bf16x8 vones;
#pragma unroll
  for (int i = 0; i < 8; ++i) vones[i] = (short)0x3F80;  // bf16 1.0

  int myrow[4], myseg[4];
#pragma unroll
  for (int r = 0; r < 4; ++r) {
    myrow[r] = qrow0 + g * 4 + r;
    myseg[r] = seg[myrow[r]];
  }
  const int seg_lo = seg[qrow0];        // min seg over wave rows (sorted)
  const int seg_hi = seg[qrow0 + 15];   // max seg over wave rows
  const int segB   = seg[qb * 64];      // min seg over block rows

  float m_i[4] = {-1e30f, -1e30f, -1e30f, -1e30f};
  f32x4 lacc = {};
  f32x4 oacc[8] = {};

  auto stage = [&](int buf, int kv0) {
#pragma unroll
    for (int i = 0; i < 4; ++i) {
      int row = i * 16 + krow_s;
      int c16 = kcol_s ^ (row & 7);
      gload16(Kbase + (size_t)(kv0 + row) * STRQKV + c16 * 8, &Ks[buf][i * 2048 + tid * 8]);
    }
#pragma unroll
    for (int i = 0; i < 4; ++i) {
      int row = i * 32 + vrow_s;
      int c16 = vcol_s ^ (row & 7);
      gload16(Vbase + (size_t)row * T_SEQ + kv0 + c16 * 8, &Vt[buf][i * 2048 + tid * 8]);
    }
  };

  const int ntiles = qb + 1;
  int t_begin = 0;
  while (t_begin < ntiles - 1 && seg[t_begin * 64 + 63] < segB) ++t_begin;

  stage(0, t_begin * 64);
  __syncthreads();
  int cur = 0;
  for (int t = t_begin; t < ntiles; ++t) {
    const int kv0 = t * 64;
    if (t + 1 < ntiles) stage(cur ^ 1, kv0 + 64);

    const int sc_lo = seg[kv0], sc_hi = seg[kv0 + 63];
    if (sc_hi >= seg_lo) {  // wave-level skip (all cols in earlier segment)
      // ---- S = Q K^T : 16 x 64 ----
      f32x4 sacc[4] = {};
      __builtin_amdgcn_s_setprio(1);
#pragma unroll
      for (int cc = 0; cc < 4; ++cc)
#pragma unroll
        for (int c = 0; c < 4; ++c) {
          bf16x8 kf = *(const bf16x8*)(&Ks[cur][(cc * 16 + lr) * 128 + ((c * 4 + g) ^ (lr & 7)) * 8]);
          sacc[cc] = mfma16(qf[c], kf, sacc[cc]);
        }
      __builtin_amdgcn_s_setprio(0);

      const bool full = (t < qb) && (sc_lo == seg_hi);  // no causal, no seg mask
      float xv[4][4];
      float mloc = -1e30f;
      if (full) {
#pragma unroll
        for (int cc = 0; cc < 4; ++cc)
#pragma unroll
          for (int r = 0; r < 4; ++r) mloc = fmaxf(mloc, sacc[cc][r]);
      } else {
        int kvseg[4];
#pragma unroll
        for (int cc = 0; cc < 4; ++cc) kvseg[cc] = seg[kv0 + cc * 16 + lr];
#pragma unroll
        for (int cc = 0; cc < 4; ++cc) {
          int kvi = kv0 + cc * 16 + lr;
#pragma unroll
          for (int r = 0; r < 4; ++r) {
            bool ok = (kvi <= myrow[r]) && (kvseg[cc] == myseg[r]);
            float x = ok ? sacc[cc][r] : -1e30f;
            xv[cc][r] = x;
            mloc = fmaxf(mloc, x);
          }
        }
      }
      float Mt = mloc;
#pragma unroll
      for (int mk = 1; mk < 64; mk <<= 1) Mt = fmaxf(Mt, __shfl_xor(Mt, mk, 64));

      float mmin = fminf(fminf(m_i[0], m_i[1]), fminf(m_i[2], m_i[3]));
      if (!__all(Mt <= mmin + 8.0f)) {
#pragma unroll
        for (int r = 0; r < 4; ++r) {
          float mn = fmaxf(m_i[r], Mt);
          float f = __expf(m_i[r] - mn);
          m_i[r] = mn;
          lacc[r] *= f;
#pragma unroll
          for (int n = 0; n < 8; ++n) oacc[n][r] *= f;
        }
      }

      if (full) {
#pragma unroll
        for (int cc = 0; cc < 4; ++cc)
#pragma unroll
          for (int r = 0; r < 4; ++r)
            Plds[wave][g * 4 + r][cc * 16 + lr] = f2bf(__expf(sacc[cc][r] - m_i[r]));
      } else {
#pragma unroll
        for (int cc = 0; cc < 4; ++cc)
#pragma unroll
          for (int r = 0; r < 4; ++r) {
            float x = xv[cc][r];
            float p = __expf(x - m_i[r]);
            Plds[wave][g * 4 + r][cc * 16 + lr] = f2bf((x > -1e29f) ? p : 0.0f);
          }
      }

      bf16x8 pf0 = *(const bf16x8*)(&Plds[wave][lr][g * 8]);
      bf16x8 pf1 = *(const bf16x8*)(&Plds[wave][lr][32 + g * 8]);
      __builtin_amdgcn_s_setprio(1);
#pragma unroll
      for (int n = 0; n < 8; ++n) {
        bf16x8 vf0 = *(const bf16x8*)(&Vt[cur][(n * 16 + lr) * 64 + (g ^ (lr & 7)) * 8]);
        oacc[n] = mfma16(pf0, vf0, oacc[n]);
        bf16x8 vf1 = *(const bf16x8*)(&Vt[cur][(n * 16 + lr) * 64 + ((4 + g) ^ (lr & 7)) * 8]);
        oacc[n] = mfma16(pf1, vf1, oacc[n]);
      }
      lacc = mfma16(pf0, vones, lacc);
      lacc = mfma16(pf1, vones, lacc);
      __builtin_amdgcn_s_setprio(0);
    }

    __syncthreads();  // prefetch drained + all waves done with buf cur
    cur ^= 1;
  }

  // epilogue: normalize, sigmoid-gate, store bf16
#pragma unroll
  for (int n = 0; n < 8; ++n)
#pragma unroll
    for (int r = 0; r < 4; ++r) {
      int row = myrow[r];
      int d = n * 16 + lr;
      float o = oacc[n][r] / lacc[r];
      float gv = bf2f(qkv[(size_t)row * STRQKV + h * 256 + 128 + d]);
      float gate = 1.0f / (1.0f + __expf(-gv));
      attnb[(size_t)row * (NH * HD) + h * HD + d] = f2bf(o * gate);
    }
}

extern "C" void kernel_launch(void* const* d_in, const int* in_sizes, int n_in,
                              void* d_out, int out_size, void* d_ws, size_t ws_size,
                              hipStream_t stream) {
  const float* hidden = (const float*)d_in[0];
  const float* cosb   = (const float*)d_in[1];
  const float* sinb   = (const float*)d_in[2];
  const int*   seg    = (const int*)d_in[3];
  // d_in[4] = position_ids (arange; causal handled by index arithmetic)
  const float* wq     = (const float*)d_in[5];
  const float* wk     = (const float*)d_in[6];
  const float* wv     = (const float*)d_in[7];
  const float* wo     = (const float*)d_in[8];
  const float* qnw    = (const float*)d_in[9];
  const float* knw    = (const float*)d_in[10];
  float* out = (float*)d_out;

  // Workspace layout — peak 48 MB with liveness-based aliasing:
  //   [0,8)    Xb (hidden bf16)                 -> dead after QKV GEMM -> Attnb
  //   [8,28)   Wqkvt [5120][2048]               -> dead after QKV GEMM ->
  //              Wot [8,16), VT [16,18)
  //   [28,48)  Cqkv [2048][5120] (q|gate|k|v; k normed/roped in place)
  char* ws = (char*)d_ws;
  const size_t MB = (size_t)1 << 20;
  unsigned short* Xb    = (unsigned short*)(ws + 0 * MB);
  unsigned short* Attnb = (unsigned short*)(ws + 0 * MB);   // alias Xb
  unsigned short* Wqkvt = (unsigned short*)(ws + 8 * MB);
  unsigned short* Wot   = (unsigned short*)(ws + 8 * MB);   // alias Wqkvt (after GEMM)
  unsigned short* VT    = (unsigned short*)(ws + 16 * MB);  // alias Wqkvt (after GEMM)
  unsigned short* Cqkv  = (unsigned short*)(ws + 28 * MB);

  convert_x<<<4096, 256, 0, stream>>>(hidden, Xb, (DMODEL * T_SEQ) / 4);
  transpose_f32_to_bf16<<<dim3(4096 / 32, DMODEL / 32), 256, 0, stream>>>(wq, Wqkvt, DMODEL, 4096);
  transpose_f32_to_bf16<<<dim3(512 / 32, DMODEL / 32), 256, 0, stream>>>(wk, Wqkvt + (size_t)KOFF * DMODEL, DMODEL, 512);
  transpose_f32_to_bf16<<<dim3(512 / 32, DMODEL / 32), 256, 0, stream>>>(wv, Wqkvt + (size_t)VOFF * DMODEL, DMODEL, 512);

  gemm_bt<unsigned short><<<dim3(STRQKV / 128, T_SEQ / 128), 256, 0, stream>>>(Xb, Wqkvt, Cqkv, T_SEQ, STRQKV, DMODEL);

  // Wqkvt dead now
  transpose_f32_to_bf16<<<dim3(DMODEL / 32, DMODEL / 32), 256, 0, stream>>>(wo, Wot, DMODEL, DMODEL);
  rms_rope_k<<<dim3(T_SEQ, NKV), 128, 0, stream>>>(Cqkv, cosb, sinb, knw);
  transpose_v<<<dim3(T_SEQ / 32, HD / 32, NKV), 256, 0, stream>>>(Cqkv, VT);

  attn_kernel<<<512, 256, 0, stream>>>(Cqkv, VT, seg, cosb, sinb, qnw, Attnb);

  gemm_bt<float><<<dim3(DMODEL / 128, T_SEQ / 128), 256, 0, stream>>>(Attnb, Wot, out, T_SEQ, DMODEL, DMODEL);
}

// Round 8
// 171.166 us; speedup vs baseline: 1.0574x; 1.0574x over previous
//
#include <hip/hip_runtime.h>

typedef __attribute__((ext_vector_type(8))) short bf16x8;
typedef __attribute__((ext_vector_type(4))) float f32x4;
typedef __attribute__((ext_vector_type(4))) unsigned short us4;

#define T_SEQ 2048
#define DMODEL 2048
#define NH 16
#define NKV 4
#define HD 128
#define STRQKV 5120   /* NH*HD*2 + 2*NKV*HD : fused QKV output row stride */
#define KOFF 4096
#define VOFF 4608
#define ATT_SCALE 0.08838834764831845f

__device__ __forceinline__ float bf2f(unsigned short u) {
  union { unsigned int u; float f; } v; v.u = ((unsigned int)u) << 16; return v.f;
}
__device__ __forceinline__ unsigned short f2bf(float f) {
  union { float f; unsigned int u; } v; v.f = f;
  unsigned int u = v.u;
  return (unsigned short)((u + 0x7fffu + ((u >> 16) & 1u)) >> 16);
}
__device__ __forceinline__ f32x4 mfma16(bf16x8 a, bf16x8 b, f32x4 c) {
  return __builtin_amdgcn_mfma_f32_16x16x32_bf16(a, b, c, 0, 0, 0);
}
__device__ __forceinline__ void gload16(const void* g, void* l) {
  __builtin_amdgcn_global_load_lds(
      (const __attribute__((address_space(1))) unsigned int*)g,
      (__attribute__((address_space(3))) unsigned int*)l, 16, 0, 0);
}

// ---------------- fp32 -> bf16 elementwise (hidden) ----------------
__global__ __launch_bounds__(256) void convert_x(const float* __restrict__ in,
                                                 unsigned short* __restrict__ out, int n4) {
  int i = blockIdx.x * 256 + threadIdx.x;
  if (i >= n4) return;
  float4 v = ((const float4*)in)[i];
  us4 o; o.x = f2bf(v.x); o.y = f2bf(v.y); o.z = f2bf(v.z); o.w = f2bf(v.w);
  ((us4*)out)[i] = o;
}

// ---------------- fp32 [K][N] -> bf16 [N][K] transpose ----------------
__global__ __launch_bounds__(256) void transpose_f32_to_bf16(
    const float* __restrict__ in, unsigned short* __restrict__ out, int K, int N) {
  __shared__ unsigned short tile[32][33];
  int nb = blockIdx.x * 32, kb = blockIdx.y * 32;
  int tx = threadIdx.x & 31, ty = threadIdx.x >> 5;
#pragma unroll
  for (int i = 0; i < 32; i += 8)
    tile[ty + i][tx] = f2bf(in[(size_t)(kb + ty + i) * N + nb + tx]);
  __syncthreads();
#pragma unroll
  for (int i = 0; i < 32; i += 8)
    out[(size_t)(nb + ty + i) * K + kb + tx] = tile[tx][ty + i];
}

// ---------------- bf16 V (inside QKV, stride 5120) -> [NKV][HD][T] ----------------
__global__ __launch_bounds__(256) void transpose_v(const unsigned short* __restrict__ qkv,
                                                   unsigned short* __restrict__ vTg) {
  __shared__ unsigned short tile[32][33];
  int tb = blockIdx.x * 32, db = blockIdx.y * 32, kvh = blockIdx.z;
  int tx = threadIdx.x & 31, ty = threadIdx.x >> 5;
#pragma unroll
  for (int i = 0; i < 32; i += 8)
    tile[ty + i][tx] = qkv[(size_t)(tb + ty + i) * STRQKV + VOFF + kvh * HD + db + tx];
  __syncthreads();
#pragma unroll
  for (int i = 0; i < 32; i += 8)
    vTg[((size_t)kvh * HD + db + ty + i) * T_SEQ + tb + tx] = tile[tx][ty + i];
}

// ---------------- GEMM: C[M][N] = A[M][K] * B^T  (B stored [N][K]) ----------------
// R6-proven structure: 128x128 tile, 4 waves, 2-buffer global_load_lds staging,
// one stage+one barrier pair per k-step. Added: bijective XCD block swizzle.
template <typename OT>
__global__ __launch_bounds__(256) void gemm_bt(const unsigned short* __restrict__ A,
                                               const unsigned short* __restrict__ B,
                                               OT* __restrict__ C, int M, int N, int K) {
  __shared__ unsigned short As[2][128 * 32];
  __shared__ unsigned short Bs[2][128 * 32];
  const int tid = threadIdx.x;
  const int wave = tid >> 6, lane = tid & 63;
  const int wr = wave >> 1, wc = wave & 1;
  const int g = lane >> 4, lr = lane & 15;

  // bijective XCD swizzle (m204): round-robin dispatch -> contiguous chunk/XCD
  const int gx = gridDim.x;
  const int nwg = gx * gridDim.y;
  int wg = blockIdx.y * gx + blockIdx.x;
  {
    const int qd = nwg >> 3, rm = nwg & 7;
    const int xcd = wg & 7, loc = wg >> 3;
    wg = (xcd < rm) ? (xcd * (qd + 1) + loc) : (rm * (qd + 1) + (xcd - rm) * qd + loc);
  }
  const int row0 = (wg / gx) * 128, col0 = (wg % gx) * 128;

  const unsigned short* Ap = A + (size_t)(row0 + (tid >> 2)) * K + (tid & 3) * 8;
  const unsigned short* Bp = B + (size_t)(col0 + (tid >> 2)) * K + (tid & 3) * 8;
  const size_t half = (size_t)64 * K;

  f32x4 acc[4][4] = {};

  auto stage = [&](int buf, int k0) {
    gload16(Ap + k0,        &As[buf][tid * 8]);
    gload16(Ap + half + k0, &As[buf][2048 + tid * 8]);
    gload16(Bp + k0,        &Bs[buf][tid * 8]);
    gload16(Bp + half + k0, &Bs[buf][2048 + tid * 8]);
  };

  stage(0, 0);
  __syncthreads();
  int cur = 0;
  for (int k0 = 0; k0 < K; k0 += 32) {
    if (k0 + 32 < K) stage(cur ^ 1, k0 + 32);

    bf16x8 af[4], bfr[4];
#pragma unroll
    for (int m = 0; m < 4; ++m) af[m] = *(const bf16x8*)(&As[cur][(wr * 64 + m * 16 + lr) * 32 + g * 8]);
#pragma unroll
    for (int n = 0; n < 4; ++n) bfr[n] = *(const bf16x8*)(&Bs[cur][(wc * 64 + n * 16 + lr) * 32 + g * 8]);
    __builtin_amdgcn_s_setprio(1);
#pragma unroll
    for (int m = 0; m < 4; ++m)
#pragma unroll
      for (int n = 0; n < 4; ++n)
        acc[m][n] = mfma16(af[m], bfr[n], acc[m][n]);
    __builtin_amdgcn_s_setprio(0);

    __syncthreads();
    cur ^= 1;
  }

#pragma unroll
  for (int m = 0; m < 4; ++m)
#pragma unroll
    for (int n = 0; n < 4; ++n)
#pragma unroll
      for (int r = 0; r < 4; ++r) {
        int row = row0 + wr * 64 + m * 16 + g * 4 + r;
        int col = col0 + wc * 64 + n * 16 + lr;
        float v = acc[m][n][r];
        if constexpr (sizeof(OT) == 2) C[(size_t)row * N + col] = f2bf(v);
        else                            C[(size_t)row * N + col] = v;
      }
}

// ---------------- RMSNorm + RoPE for K only (IN PLACE in QKV buffer) ----------------
__global__ __launch_bounds__(128) void rms_rope_k(
    unsigned short* __restrict__ qkv,
    const float* __restrict__ cosb, const float* __restrict__ sinb,
    const float* __restrict__ knw) {
  int t = blockIdx.x;
  int kh = blockIdx.y;
  int d = threadIdx.x;
  size_t addr = (size_t)t * STRQKV + KOFF + kh * HD + d;
  float x = bf2f(qkv[addr]);
  float ss = x * x;
#pragma unroll
  for (int mk = 1; mk < 64; mk <<= 1) ss += __shfl_xor(ss, mk, 64);
  __shared__ float red[2];
  __shared__ float xs[128];
  if ((d & 63) == 0) red[d >> 6] = ss;
  __syncthreads();
  float rstd = rsqrtf((red[0] + red[1]) * (1.0f / 128.0f) + 1e-6f);
  float xn = x * rstd * knw[d];
  xs[d] = xn;
  __syncthreads();
  float other = (d < 64) ? -xs[d + 64] : xs[d - 64];
  float c = cosb[(size_t)t * HD + d];
  float s = sinb[(size_t)t * HD + d];
  qkv[addr] = f2bf(xn * c + other * s);
}

// ---------------- Flash attention + gate (Q norm/rope fused) ----------------
// 512 blocks x 4 waves; wave = 16 q-rows. KVBLK=32, FOUR buffers, depth-2
// prefetch with counted vmcnt (never 0 in steady state), ONE s_barrier/tile.
// Softmax with NO max-tracking: RMSNorm bounds |logit| <= sqrt(128)=11.32,
// so exp(x) is overflow-safe in f32/bf16 and softmax = exp(x)/sum exp(x)
// directly (shift-invariance). Removes wave reduce + rescale entirely.
__global__ __launch_bounds__(256) void attn_kernel(
    const unsigned short* __restrict__ qkv, const unsigned short* __restrict__ vTg,
    const int* __restrict__ seg,
    const float* __restrict__ cosb, const float* __restrict__ sinb,
    const float* __restrict__ qnw,
    unsigned short* __restrict__ attnb) {
  const int bid = blockIdx.x;
  const int h = bid & 15;
  const int j = bid >> 4;
  const int qb = (j < 16) ? j : 47 - j;   // co-resident pairing: qb + (31-qb)
  const int kvh = h >> 2;
  const int tid = threadIdx.x;
  const int wave = tid >> 6, lane = tid & 63;
  const int g = lane >> 4, lr = lane & 15;
  const int qrow0 = qb * 64 + wave * 16;

  __shared__ unsigned short Ks[4][32 * 128];   // 32 KB
  __shared__ unsigned short Vt[4][128 * 32];   // 32 KB
  __shared__ unsigned short Plds[4][16][40];   // 5 KB

  const unsigned short* Kbase = qkv + KOFF + kvh * HD;         // row stride STRQKV
  const unsigned short* Vbase = vTg + (size_t)kvh * HD * T_SEQ;

  // stage one 32-wide KV tile: K[32][128] + V^T[128][32], 4 loads/thread.
  // XOR involution on 16B col-chunks (K: ^row&7 over 16 slots; V: ^row&3 over 4).
  auto stage = [&](int buf, int kv0) {
#pragma unroll
    for (int i = 0; i < 2; ++i) {
      int row = i * 16 + (tid >> 4);
      int c16 = (tid & 15) ^ (row & 7);
      gload16(Kbase + (size_t)(kv0 + row) * STRQKV + c16 * 8, &Ks[buf][i * 2048 + tid * 8]);
    }
#pragma unroll
    for (int i = 0; i < 2; ++i) {
      int row = i * 64 + (tid >> 2);
      int c16 = (tid & 3) ^ (row & 3);
      gload16(Vbase + (size_t)row * T_SEQ + kv0 + c16 * 8, &Vt[buf][i * 2048 + tid * 8]);
    }
  };

  const int ntiles = qb * 2 + 2;
  const int segB = seg[qb * 64];
  int t_begin = 0;
  while (t_begin < ntiles - 1 && seg[t_begin * 32 + 31] < segB) ++t_begin;

  stage(t_begin & 3, t_begin * 32);
  if (t_begin + 1 < ntiles) stage((t_begin + 1) & 3, t_begin * 32 + 32);

  // ---- fused Q RMSNorm + RoPE + scale (overlaps staging latency) ----
  const int t0 = qrow0 + lr;
  float xn[4][8];
  {
    float ssl = 0.f;
#pragma unroll
    for (int c = 0; c < 4; ++c) {
      bf16x8 tq = *(const bf16x8*)(qkv + (size_t)t0 * STRQKV + h * 256 + c * 32 + g * 8);
#pragma unroll
      for (int i = 0; i < 8; ++i) {
        float x = bf2f((unsigned short)tq[i]);
        xn[c][i] = x;
        ssl += x * x;
      }
    }
    ssl += __shfl_xor(ssl, 16, 64);
    ssl += __shfl_xor(ssl, 32, 64);
    float rstd = rsqrtf(ssl * (1.0f / 128.0f) + 1e-6f);
#pragma unroll
    for (int c = 0; c < 4; ++c)
#pragma unroll
      for (int i = 0; i < 8; ++i)
        xn[c][i] *= rstd * qnw[c * 32 + g * 8 + i];
  }
  bf16x8 qf[4];
#pragma unroll
  for (int c = 0; c < 4; ++c)
#pragma unroll
    for (int i = 0; i < 8; ++i) {
      int d = c * 32 + g * 8 + i;
      float rot = (c < 2) ? -xn[c + 2][i] : xn[c - 2][i];
      float ov = xn[c][i] * cosb[(size_t)t0 * HD + d] + rot * sinb[(size_t)t0 * HD + d];
      qf[c][i] = (short)f2bf(ov * ATT_SCALE);
    }

  bf16x8 vones;
#pragma unroll
  for (int i = 0; i < 8; ++i) vones[i] = (short)0x3F80;  // bf16 1.0

  int myrow[4], myseg[4];
#pragma unroll
  for (int r = 0; r < 4; ++r) {
    myrow[r] = qrow0 + g * 4 + r;
    myseg[r] = seg[myrow[r]];
  }
  const int seg_lo = seg[qrow0];
  const int seg_hi = seg[qrow0 + 15];

  f32x4 lacc = {};
  f32x4 oacc[8] = {};

  for (int t = t_begin; t < ntiles; ++t) {
    const int kv0 = t * 32;
    if (t + 2 < ntiles) {
      stage((t + 2) & 3, kv0 + 64);
      asm volatile("s_waitcnt vmcnt(8)" ::: "memory");   // tile t landed; t+1,t+2 in flight
    } else if (t + 1 < ntiles) {
      asm volatile("s_waitcnt vmcnt(4)" ::: "memory");
    } else {
      asm volatile("s_waitcnt vmcnt(0)" ::: "memory");
    }
    __builtin_amdgcn_s_barrier();
    __builtin_amdgcn_sched_barrier(0);

    if (kv0 < qrow0 + 16 && seg[kv0 + 31] >= seg_lo) {  // wave-level causal/seg skip
      const unsigned short* ks = Ks[t & 3];
      const unsigned short* vt = Vt[t & 3];

      // ---- S = Q K^T : 16 x 32 ----
      f32x4 sacc[2] = {};
      __builtin_amdgcn_s_setprio(1);
#pragma unroll
      for (int cc = 0; cc < 2; ++cc)
#pragma unroll
        for (int c = 0; c < 4; ++c) {
          int row = cc * 16 + lr;
          bf16x8 kf = *(const bf16x8*)(&ks[row * 128 + (((c * 4 + g) ^ (row & 7)) * 8)]);
          sacc[cc] = mfma16(qf[c], kf, sacc[cc]);
        }
      __builtin_amdgcn_s_setprio(0);

      // ---- P = exp(S) (no max shift; bounded by construction) ----
      const bool full = (kv0 + 32 <= qrow0) && (seg[kv0] == seg_hi);
      if (full) {
#pragma unroll
        for (int cc = 0; cc < 2; ++cc)
#pragma unroll
          for (int r = 0; r < 4; ++r)
            Plds[wave][g * 4 + r][cc * 16 + lr] = f2bf(__expf(sacc[cc][r]));
      } else {
#pragma unroll
        for (int cc = 0; cc < 2; ++cc) {
          int kvi = kv0 + cc * 16 + lr;
          int ksg = seg[kvi];
#pragma unroll
          for (int r = 0; r < 4; ++r) {
            bool ok = (kvi <= myrow[r]) && (ksg == myseg[r]);
            float p = __expf(sacc[cc][r]);
            Plds[wave][g * 4 + r][cc * 16 + lr] = f2bf(ok ? p : 0.0f);
          }
        }
      }

      // ---- PV: O += P[16x32] * V^T ; row-sum via ones-vector MFMA ----
      bf16x8 pf = *(const bf16x8*)(&Plds[wave][lr][g * 8]);
      __builtin_amdgcn_s_setprio(1);
#pragma unroll
      for (int n = 0; n < 8; ++n) {
        bf16x8 vf = *(const bf16x8*)(&vt[(n * 16 + lr) * 32 + ((g ^ (lr & 3)) * 8)]);
        oacc[n] = mfma16(pf, vf, oacc[n]);
      }
      lacc = mfma16(pf, vones, lacc);
      __builtin_amdgcn_s_setprio(0);
    }
  }

  // epilogue: normalize, sigmoid-gate, store bf16
#pragma unroll
  for (int n = 0; n < 8; ++n)
#pragma unroll
    for (int r = 0; r < 4; ++r) {
      int row = myrow[r];
      int d = n * 16 + lr;
      float o = oacc[n][r] / lacc[r];
      float gv = bf2f(qkv[(size_t)row * STRQKV + h * 256 + 128 + d]);
      float gate = 1.0f / (1.0f + __expf(-gv));
      attnb[(size_t)row * (NH * HD) + h * HD + d] = f2bf(o * gate);
    }
}

extern "C" void kernel_launch(void* const* d_in, const int* in_sizes, int n_in,
                              void* d_out, int out_size, void* d_ws, size_t ws_size,
                              hipStream_t stream) {
  const float* hidden = (const float*)d_in[0];
  const float* cosb   = (const float*)d_in[1];
  const float* sinb   = (const float*)d_in[2];
  const int*   seg    = (const int*)d_in[3];
  // d_in[4] = position_ids (arange; causal handled by index arithmetic)
  const float* wq     = (const float*)d_in[5];
  const float* wk     = (const float*)d_in[6];
  const float* wv     = (const float*)d_in[7];
  const float* wo     = (const float*)d_in[8];
  const float* qnw    = (const float*)d_in[9];
  const float* knw    = (const float*)d_in[10];
  float* out = (float*)d_out;

  // Workspace layout — peak 48 MB with liveness-based aliasing:
  //   [0,8)    Xb (hidden bf16)   -> dead after QKV GEMM -> Attnb
  //   [8,28)   Wqkvt [5120][2048] -> dead after QKV GEMM -> Wot [8,16), VT [16,18)
  //   [28,48)  Cqkv [2048][5120]  (q|gate|k|v; k normed/roped in place)
  char* ws = (char*)d_ws;
  const size_t MB = (size_t)1 << 20;
  unsigned short* Xb    = (unsigned short*)(ws + 0 * MB);
  unsigned short* Attnb = (unsigned short*)(ws + 0 * MB);
  unsigned short* Wqkvt = (unsigned short*)(ws + 8 * MB);
  unsigned short* Wot   = (unsigned short*)(ws + 8 * MB);
  unsigned short* VT    = (unsigned short*)(ws + 16 * MB);
  unsigned short* Cqkv  = (unsigned short*)(ws + 28 * MB);

  convert_x<<<4096, 256, 0, stream>>>(hidden, Xb, (DMODEL * T_SEQ) / 4);
  transpose_f32_to_bf16<<<dim3(4096 / 32, DMODEL / 32), 256, 0, stream>>>(wq, Wqkvt, DMODEL, 4096);
  transpose_f32_to_bf16<<<dim3(512 / 32, DMODEL / 32), 256, 0, stream>>>(wk, Wqkvt + (size_t)KOFF * DMODEL, DMODEL, 512);
  transpose_f32_to_bf16<<<dim3(512 / 32, DMODEL / 32), 256, 0, stream>>>(wv, Wqkvt + (size_t)VOFF * DMODEL, DMODEL, 512);

  gemm_bt<unsigned short><<<dim3(STRQKV / 128, T_SEQ / 128), 256, 0, stream>>>(Xb, Wqkvt, Cqkv, T_SEQ, STRQKV, DMODEL);

  transpose_f32_to_bf16<<<dim3(DMODEL / 32, DMODEL / 32), 256, 0, stream>>>(wo, Wot, DMODEL, DMODEL);
  rms_rope_k<<<dim3(T_SEQ, NKV), 128, 0, stream>>>(Cqkv, cosb, sinb, knw);
  transpose_v<<<dim3(T_SEQ / 32, HD / 32, NKV), 256, 0, stream>>>(Cqkv, VT);

  attn_kernel<<<512, 256, 0, stream>>>(Cqkv, VT, seg, cosb, sinb, qnw, Attnb);

  gemm_bt<float><<<dim3(DMODEL / 128, T_SEQ / 128), 256, 0, stream>>>(Attnb, Wot, out, T_SEQ, DMODEL, DMODEL);
}